// Round 16
// baseline (502.807 us; speedup 1.0000x reference)
//
#include <hip/hip_runtime.h>
#include <cstdint>
#include <cstddef>

#define NN 100000
#define NE 1600000
#define NTOT (NE + NN)      // 1700000 edges incl self-loops
#define HF 128
#define OF 64
#define SHARD 12500         // NN/8 dst-range per XCD
#define BCHUNK 2048         // edges per k_bin block
#define BCAP 210000         // per-shard bin capacity (mean 200K, +24 sigma)
#define KB 32               // blocks per shard in cnt/fill

// Hidden-feature buffers (xb, m, h_l) use the MFMA-native PERMUTED layout:
// stored position p holds logical col c with p = (c&15)*8 + (c>>4),
// i.e. c = (p&7)*16 + (p>>3). W/Wjk get the inverse permutation on their
// k-dim in k_prep, so all matmuls are invariant. This makes both the MFMA
// epilogue store and the gather 16B/lane coalesced.

typedef short bfrag_t __attribute__((ext_vector_type(8)));   // 8 bf16 = 4 VGPR
typedef float f4v     __attribute__((ext_vector_type(4)));   // MFMA acc

// ---------------- helpers ----------------

__device__ __forceinline__ unsigned int f2bf_rne(float f) {
    unsigned int u = __float_as_uint(f);
    return (u + 0x7fffu + ((u >> 16) & 1u)) >> 16;
}
__device__ __forceinline__ unsigned int pack_bf2(float lo, float hi) {
    return f2bf_rne(lo) | (f2bf_rne(hi) << 16);
}

// ---------------- graph preprocessing ----------------

__global__ __launch_bounds__(64) void k_init(int* gcnt) {
    if (threadIdx.x < 8) gcnt[threadIdx.x] = 0;
}

__device__ __forceinline__ int nt_load(const int* p) {
    return __builtin_nontemporal_load(p);
}

// Single-pass shard binning with per-block int64/int32 self-detection.
__global__ __launch_bounds__(256) void k_bin(const int* __restrict__ ei,
                                             int* __restrict__ gcnt,
                                             uint2* __restrict__ binbuf) {
    __shared__ uint2 bins[8][640];     // 40 KB; 640 cap = +32 sigma vs mean 256
    __shared__ int cnt[8], base[8], anynz;
    int tid = threadIdx.x;
    if (tid < 8) cnt[tid] = 0;
    if (tid == 0) anynz = 0;
    __syncthreads();
    int ebeg = blockIdx.x * BCHUNK;
    int eend = min(NE, ebeg + BCHUNK);
    int v = 0;
    for (int e = ebeg + tid; e < eend; e += 256) v |= nt_load(&ei[2 * e + 1]);
    if (v) anynz = 1;                  // benign race: all writers store 1
    __syncthreads();
    bool is64 = (anynz == 0);
    for (int e = ebeg + tid; e < eend; e += 256) {
        int d = is64 ? nt_load(&ei[2 * (NE + e)]) : nt_load(&ei[NE + e]);
        int s = is64 ? nt_load(&ei[2 * e])        : nt_load(&ei[e]);
        int x = (unsigned)d / SHARD;
        int p = atomicAdd(&cnt[x], 1);
        if (p < 640) bins[x][p] = make_uint2((unsigned)d, (unsigned)s);
    }
    __syncthreads();
    if (tid < 8) {
        int c = min(cnt[tid], 640);
        cnt[tid] = c;
        base[tid] = atomicAdd(&gcnt[tid], c);
    }
    __syncthreads();
    for (int x = 0; x < 8; ++x) {
        int c = cnt[x], b0 = base[x];
        for (int i = tid; i < c; i += 256)
            if (b0 + i < BCAP) binbuf[(size_t)x * BCAP + b0 + i] = bins[x][i];
    }
}

// Pass A: per-(shard,block) LDS count-histogram of its record chunk.
__global__ __launch_bounds__(256) void k_cnt(const int* __restrict__ gcnt,
                                             const uint2* __restrict__ binbuf,
                                             int* __restrict__ blockhist) {
    __shared__ int hist[SHARD];        // 50 KB
    int tid = threadIdx.x;
    int x = blockIdx.x & 7, kb = blockIdx.x >> 3;
    int n = min(gcnt[x], BCAP);
    int chunk = (n + KB - 1) / KB;
    int beg = kb * chunk, end = min(n, beg + chunk);
    for (int i = tid; i < SHARD; i += 256) hist[i] = 0;
    __syncthreads();
    for (int i = beg + tid; i < end; i += 256) {
        uint2 r = binbuf[(size_t)x * BCAP + i];
        atomicAdd(&hist[r.x - (unsigned)x * SHARD], 1);
    }
    __syncthreads();
    int* bh = blockhist + ((size_t)x * KB + kb) * SHARD;
    for (int i = tid; i < SHARD; i += 256) bh[i] = hist[i];
}

// Column scan: per node, exclusive-scan the KB per-block counts (in place)
// and write deg = 1 + total (self-loop).
__global__ __launch_bounds__(256) void k_colscan(int* __restrict__ blockhist,
                                                 int* __restrict__ deg) {
    int i = blockIdx.x * 256 + threadIdx.x;
    if (i >= NN) return;
    int x = i / SHARD, ln = i % SHARD;
    int* col = blockhist + (size_t)x * KB * SHARD + ln;
    int s = 0;
#pragma unroll
    for (int kb = 0; kb < KB; ++kb) {
        int c = col[(size_t)kb * SHARD];
        col[(size_t)kb * SHARD] = s;
        s += c;
    }
    deg[i] = 1 + s;
}

// exclusive scan of deg[N] -> rowptr (partial), also dinv = rsqrt(deg)
__global__ __launch_bounds__(256) void k_scanA(const int* deg, int* rowptr, int* bsum,
                                               float* dinv) {
    __shared__ int sh[256];
    int tid = threadIdx.x;
    int base = blockIdx.x * 1024 + tid * 4;
    int v0 = 0, v1 = 0, v2 = 0, v3 = 0;
    if (base + 0 < NN) v0 = deg[base + 0];
    if (base + 1 < NN) v1 = deg[base + 1];
    if (base + 2 < NN) v2 = deg[base + 2];
    if (base + 3 < NN) v3 = deg[base + 3];
    if (base + 0 < NN) dinv[base + 0] = rsqrtf((float)v0);
    if (base + 1 < NN) dinv[base + 1] = rsqrtf((float)v1);
    if (base + 2 < NN) dinv[base + 2] = rsqrtf((float)v2);
    if (base + 3 < NN) dinv[base + 3] = rsqrtf((float)v3);
    int s = v0 + v1 + v2 + v3;
    sh[tid] = s;
    __syncthreads();
    for (int off = 1; off < 256; off <<= 1) {
        int t = (tid >= off) ? sh[tid - off] : 0;
        __syncthreads();
        sh[tid] += t;
        __syncthreads();
    }
    int run = sh[tid] - s;
    if (base + 0 < NN) rowptr[base + 0] = run; run += v0;
    if (base + 1 < NN) rowptr[base + 1] = run; run += v1;
    if (base + 2 < NN) rowptr[base + 2] = run; run += v2;
    if (base + 3 < NN) rowptr[base + 3] = run;
    if (tid == 255) bsum[blockIdx.x] = sh[255];
}

__global__ __launch_bounds__(128) void k_scanB(const int* bsum, int* boff, int* rowptr) {
    __shared__ int sh[128];
    int tid = threadIdx.x;
    int v = (tid < 98) ? bsum[tid] : 0;
    sh[tid] = v;
    __syncthreads();
    for (int off = 1; off < 128; off <<= 1) {
        int t = (tid >= off) ? sh[tid - off] : 0;
        __syncthreads();
        sh[tid] += t;
        __syncthreads();
    }
    if (tid < 98) boff[tid] = sh[tid] - v;
    if (tid == 0) rowptr[NN] = NTOT;
}

// finalize rowptr AND place the self-loop in slot 0 of each row
__global__ __launch_bounds__(256) void k_scanC(int* rowptr, const int* boff, int* csr) {
    int i = blockIdx.x * 256 + threadIdx.x;
    if (i < NN) {
        int r = rowptr[i] + boff[i >> 10];
        rowptr[i] = r;
        csr[r] = i;          // self-loop (edge ranks start at 1)
    }
}

// Pass B: re-read records, assign local ranks via LDS atomics, write csr.
__global__ __launch_bounds__(256) void k_fill(const int* __restrict__ gcnt,
                                              const uint2* __restrict__ binbuf,
                                              const int* __restrict__ blockhist,
                                              const int* __restrict__ rowptr,
                                              int* __restrict__ csr) {
    __shared__ int lrank[SHARD];       // 50 KB
    int tid = threadIdx.x;
    int x = blockIdx.x & 7, kb = blockIdx.x >> 3;
    int n = min(gcnt[x], BCAP);
    int chunk = (n + KB - 1) / KB;
    int beg = kb * chunk, end = min(n, beg + chunk);
    for (int i = tid; i < SHARD; i += 256) lrank[i] = 0;
    __syncthreads();
    const int* bh = blockhist + ((size_t)x * KB + kb) * SHARD;
    for (int i = beg + tid; i < end; i += 256) {
        uint2 r = binbuf[(size_t)x * BCAP + i];
        int ln = r.x - (unsigned)x * SHARD;
        int lr = atomicAdd(&lrank[ln], 1);
        csr[rowptr[r.x] + 1 + bh[ln] + lr] = (int)r.y;
    }
}

// ---------------- x f32 -> bf16, PERMUTED layout ----------------
// thread (row, lj): loads x[row][i*16+lj] (i=0..7; per-i the 16 lanes read
// 64 B coalesced), packs into the uint4 at stored positions lj*8..lj*8+7.
__global__ __launch_bounds__(256) void k_xcvt(const float* __restrict__ x,
                                              uint4* __restrict__ xb4) {
    int t = blockIdx.x * 256 + threadIdx.x;
    if (t >= NN * 16) return;
    int row = t >> 4, lj = t & 15;
    const float* xr = x + (size_t)row * 128 + lj;
    uint4 o;
    o.x = pack_bf2(xr[0],  xr[16]);
    o.y = pack_bf2(xr[32], xr[48]);
    o.z = pack_bf2(xr[64], xr[80]);
    o.w = pack_bf2(xr[96], xr[112]);
    xb4[(size_t)row * 16 + lj] = o;
}

// ---------------- weight prep: bf16 + transpose + k-dim permutation ----------------
// WT[l][n*128+p]  = bf16(W_l[pi_inv(p)][n]),  pi_inv(p) = (p&7)*16 + (p>>3)
// WjT[l][n*128+p] = bf16(linW[l*128+pi_inv(p)][n])
__global__ __launch_bounds__(256) void k_prep(const float* __restrict__ W0,
                                              const float* __restrict__ W1,
                                              const float* __restrict__ W2,
                                              const float* __restrict__ W3,
                                              const float* __restrict__ linW,
                                              unsigned short* __restrict__ WT,
                                              unsigned short* __restrict__ WjT) {
    int idx = blockIdx.x * 256 + threadIdx.x;
    if (idx < 4 * 128 * 128) {
        int l = idx >> 14, r = idx & 16383, n = r >> 7, p = r & 127;
        int c = (p & 7) * 16 + (p >> 3);
        const float* Wl = (l == 0) ? W0 : (l == 1) ? W1 : (l == 2) ? W2 : W3;
        WT[idx] = (unsigned short)f2bf_rne(Wl[c * 128 + n]);
    } else if (idx < 4 * 128 * 128 + 4 * 64 * 128) {
        int i2 = idx - 65536;
        int l = i2 >> 13, r = i2 & 8191, n = r >> 7, p = r & 127;
        int c = (p & 7) * 16 + (p >> 3);
        WjT[i2] = (unsigned short)f2bf_rne(linW[(size_t)(l * 128 + c) * 64 + n]);
    }
}

// ---------------- MFMA matmul: m = bf16(dinv * (A @ W)), permuted I/O ----------------
// A (permuted bf16 [N][128]): fragments direct from global, contiguous 16 B/lane.
// Epilogue: lane r15's 8 C-cols {nb*16+r15} map to stored positions r15*8+nb
// -> ONE coalesced uint4 store per reg-row (16 lanes = 256 B).
__global__ __launch_bounds__(256) void k_mmf(const unsigned short* __restrict__ A,
                                             const unsigned short* __restrict__ WT,
                                             const float* __restrict__ dinv,
                                             uint4* __restrict__ m4o) {
    __shared__ unsigned short Wlds[128 * 128];   // 32 KB
    int tid = threadIdx.x;
    int row0 = blockIdx.x * 64;

    for (int c = tid; c < 2048; c += 256) {       // W^T, swizzled
        int row = c >> 4, c16 = c & 15;
        uint4 v = *(const uint4*)&WT[row * 128 + c16 * 8];
        *(uint4*)((char*)Wlds + row * 256 + ((c16 * 16) ^ ((row & 7) << 4))) = v;
    }

    int lane = tid & 63, w = tid >> 6;
    int r15 = lane & 15, q = lane >> 4;
    int xo = (r15 & 7) << 4;

    int arow = row0 + 16 * w + r15;
    bool av = arow < NN;
    bfrag_t afr[4];
#pragma unroll
    for (int ks = 0; ks < 4; ++ks) {
        bfrag_t z = {0, 0, 0, 0, 0, 0, 0, 0};
        afr[ks] = av ? *(const bfrag_t*)&A[(size_t)arow * 128 + ks * 32 + q * 8] : z;
    }
    __syncthreads();

    f4v acc[8];
#pragma unroll
    for (int i = 0; i < 8; ++i) acc[i] = (f4v){0.f, 0.f, 0.f, 0.f};

#pragma unroll
    for (int ks = 0; ks < 4; ++ks) {
        int ko = ks * 64 + q * 16;
#pragma unroll
        for (int nb = 0; nb < 8; ++nb) {
            bfrag_t b = *(const bfrag_t*)((const char*)Wlds + (nb * 16 + r15) * 256 + (ko ^ xo));
            acc[nb] = __builtin_amdgcn_mfma_f32_16x16x32_bf16(afr[ks], b, acc[nb], 0, 0, 0);
        }
    }

#pragma unroll
    for (int reg = 0; reg < 4; ++reg) {
        int gr = row0 + 16 * w + q * 4 + reg;
        if (gr < NN) {
            float sc = dinv[gr];
            uint4 o;
            o.x = pack_bf2(acc[0][reg] * sc, acc[1][reg] * sc);
            o.y = pack_bf2(acc[2][reg] * sc, acc[3][reg] * sc);
            o.z = pack_bf2(acc[4][reg] * sc, acc[5][reg] * sc);
            o.w = pack_bf2(acc[6][reg] * sc, acc[7][reg] * sc);
            m4o[(size_t)gr * 16 + r15] = o;      // stored positions r15*8..+7
        }
    }
}

// h_out[d][:] = bf16(relu(dinv[d] * sum_s m[s][:] + b)), permuted layout.
// One wave per node; 4 groups of 16 lanes; per step 4 predicated broadcast
// csr loads + 4 independent row-gathers (16 B/lane) — no shuffles at all.
// a[q] holds logical col q*16+lj (permuted); stored slot order matches.
__global__ __launch_bounds__(256) void k_agg(const int* __restrict__ rowptr,
                                             const int* __restrict__ csr,
                                             const uint4* __restrict__ m4,
                                             const float* __restrict__ dinv,
                                             const float* __restrict__ bias,
                                             uint4* __restrict__ outb) {
    int w = threadIdx.x >> 6, lane = threadIdx.x & 63;
    int grp = lane >> 4, lj = lane & 15;
    int node = blockIdx.x * 4 + w;
    if (node >= NN) return;
    int beg = rowptr[node], end = rowptr[node + 1];

    float a[8];
#pragma unroll
    for (int q = 0; q < 8; ++q) a[q] = 0.f;

    auto acc8 = [&](uint4 v) {
        a[0] += __uint_as_float(v.x << 16);
        a[1] += __uint_as_float(v.x & 0xffff0000u);
        a[2] += __uint_as_float(v.y << 16);
        a[3] += __uint_as_float(v.y & 0xffff0000u);
        a[4] += __uint_as_float(v.z << 16);
        a[5] += __uint_as_float(v.z & 0xffff0000u);
        a[6] += __uint_as_float(v.w << 16);
        a[7] += __uint_as_float(v.w & 0xffff0000u);
    };

    for (int e = beg; e < end; e += 16) {
        int e0 = e + grp, e1 = e0 + 4, e2 = e0 + 8, e3 = e0 + 12;
        int s0 = (e0 < end) ? csr[e0] : 0;
        int s1 = (e1 < end) ? csr[e1] : 0;
        int s2 = (e2 < end) ? csr[e2] : 0;
        int s3 = (e3 < end) ? csr[e3] : 0;
        if (e0 < end) acc8(m4[(size_t)s0 * 16 + lj]);
        if (e1 < end) acc8(m4[(size_t)s1 * 16 + lj]);
        if (e2 < end) acc8(m4[(size_t)s2 * 16 + lj]);
        if (e3 < end) acc8(m4[(size_t)s3 * 16 + lj]);
    }
#pragma unroll
    for (int q = 0; q < 8; ++q) a[q] += __shfl_xor(a[q], 16);
#pragma unroll
    for (int q = 0; q < 8; ++q) a[q] += __shfl_xor(a[q], 32);

    if (grp == 0) {
        float sc = dinv[node];
        float r[8];
#pragma unroll
        for (int q = 0; q < 8; ++q)
            r[q] = fmaxf(a[q] * sc + bias[q * 16 + lj], 0.f);
        uint4 o;
        o.x = pack_bf2(r[0], r[1]);
        o.y = pack_bf2(r[2], r[3]);
        o.z = pack_bf2(r[4], r[5]);
        o.w = pack_bf2(r[6], r[7]);
        outb[(size_t)node * 16 + lj] = o;
    }
}

// ---------------- final: logits = sum_l h_l @ Wjk_l + linb; log_softmax ----------------
__global__ __launch_bounds__(256) void k_jk4(const unsigned short* __restrict__ h0,
                                             const unsigned short* __restrict__ h1,
                                             const unsigned short* __restrict__ h2,
                                             const unsigned short* __restrict__ h3,
                                             const unsigned short* __restrict__ WjT,
                                             const float* __restrict__ linb,
                                             float* __restrict__ out) {
    __shared__ unsigned short Wjlds[4 * 64 * 128];   // 64 KB, swizzled
    int tid = threadIdx.x;
    int row0 = blockIdx.x * 64;

    for (int c = tid; c < 4096; c += 256) {      // 256 rows (l*64+n) x 128
        int row = c >> 4, c16 = c & 15;
        uint4 v = *(const uint4*)&WjT[row * 128 + c16 * 8];
        *(uint4*)((char*)Wjlds + row * 256 + ((c16 * 16) ^ ((row & 7) << 4))) = v;
    }

    int lane = tid & 63, w = tid >> 6;
    int r15 = lane & 15, q = lane >> 4;
    int xo = (r15 & 7) << 4;
    int arow = row0 + 16 * w + r15;
    bool av = arow < NN;
    const unsigned short* hs[4] = {h0, h1, h2, h3};

    __syncthreads();

    f4v accj[4];
#pragma unroll
    for (int i = 0; i < 4; ++i) accj[i] = (f4v){0.f, 0.f, 0.f, 0.f};

#pragma unroll
    for (int l = 0; l < 4; ++l) {
        bfrag_t afr[4];
#pragma unroll
        for (int ks = 0; ks < 4; ++ks) {
            bfrag_t z = {0, 0, 0, 0, 0, 0, 0, 0};
            afr[ks] = av ? *(const bfrag_t*)&hs[l][(size_t)arow * 128 + ks * 32 + q * 8] : z;
        }
#pragma unroll
        for (int ks = 0; ks < 4; ++ks) {
            int ko = ks * 64 + q * 16;
#pragma unroll
            for (int jb = 0; jb < 4; ++jb) {
                bfrag_t b = *(const bfrag_t*)((const char*)Wjlds
                            + (l * 64 + jb * 16 + r15) * 256 + (ko ^ xo));
                accj[jb] = __builtin_amdgcn_mfma_f32_16x16x32_bf16(afr[ks], b, accj[jb], 0, 0, 0);
            }
        }
    }

#pragma unroll
    for (int reg = 0; reg < 4; ++reg) {
        int gr = row0 + 16 * w + q * 4 + reg;    // uniform across the 16-lane group
        float v0 = accj[0][reg] + linb[r15];
        float v1 = accj[1][reg] + linb[16 + r15];
        float v2 = accj[2][reg] + linb[32 + r15];
        float v3 = accj[3][reg] + linb[48 + r15];
        float mx = fmaxf(fmaxf(v0, v1), fmaxf(v2, v3));
#pragma unroll
        for (int s = 1; s < 16; s <<= 1) mx = fmaxf(mx, __shfl_xor(mx, s, 16));
        float sum = expf(v0 - mx) + expf(v1 - mx) + expf(v2 - mx) + expf(v3 - mx);
#pragma unroll
        for (int s = 1; s < 16; s <<= 1) sum += __shfl_xor(sum, s, 16);
        float ls = logf(sum) + mx;
        if (gr < NN) {
            out[(size_t)gr * 64 + r15]      = v0 - ls;
            out[(size_t)gr * 64 + 16 + r15] = v1 - ls;
            out[(size_t)gr * 64 + 32 + r15] = v2 - ls;
            out[(size_t)gr * 64 + 48 + r15] = v3 - ls;
        }
    }
}

// ---------------- launch ----------------

extern "C" void kernel_launch(void* const* d_in, const int* in_sizes, int n_in,
                              void* d_out, int out_size, void* d_ws, size_t ws_size,
                              hipStream_t stream) {
    const float* x    = (const float*)d_in[0];
    const int*   ei   = (const int*)d_in[1];
    const float* W[4] = {(const float*)d_in[2], (const float*)d_in[4],
                         (const float*)d_in[6], (const float*)d_in[8]};
    const float* b[4] = {(const float*)d_in[3], (const float*)d_in[5],
                         (const float*)d_in[7], (const float*)d_in[9]};
    const float* linW = (const float*)d_in[10];
    const float* linb = (const float*)d_in[11];
    float* out = (float*)d_out;

    char* wp = (char*)d_ws;
    auto alloc = [&](size_t bytes) {
        void* p = (void*)wp;
        wp += (bytes + 255) & ~(size_t)255;
        return p;
    };
    int*   gcnt    = (int*)  alloc(32);
    int*   deg     = (int*)  alloc((size_t)NN * 4);
    float* dinv    = (float*)alloc((size_t)NN * 4);
    int*   rowptr  = (int*)  alloc((size_t)(NN + 1) * 4);
    int*   bsum    = (int*)  alloc(512);
    int*   boff    = (int*)  alloc(512);
    int*   csr     = (int*)  alloc((size_t)NTOT * 4);
    uint2* binbuf  = (uint2*)alloc((size_t)8 * BCAP * 8);
    int*   blockhist = (int*)alloc((size_t)8 * KB * SHARD * 4);   // 12.8 MB
    unsigned short* WT  = (unsigned short*)alloc((size_t)4 * 128 * 128 * 2);
    unsigned short* WjT = (unsigned short*)alloc((size_t)4 * 64 * 128 * 2);
    unsigned short* xb   = (unsigned short*)alloc((size_t)NN * 128 * 2);  // permuted x
    unsigned short* bufM = (unsigned short*)alloc((size_t)NN * 128 * 2);  // messages
    unsigned short* h[4];
    for (int l = 0; l < 4; ++l)
        h[l] = (unsigned short*)alloc((size_t)NN * 128 * 2);              // bf16 h_l

    dim3 blk(256);
    k_init   <<<1, dim3(64), 0, stream>>>(gcnt);
    k_prep   <<<384, blk, 0, stream>>>(W[0], W[1], W[2], W[3], linW, WT, WjT);
    k_xcvt   <<<6250, blk, 0, stream>>>(x, (uint4*)xb);
    k_bin    <<<(NE + BCHUNK - 1) / BCHUNK, blk, 0, stream>>>(ei, gcnt, binbuf);
    k_cnt    <<<8 * KB, blk, 0, stream>>>(gcnt, binbuf, blockhist);
    k_colscan<<<391, blk, 0, stream>>>(blockhist, deg);
    k_scanA  <<<98, blk, 0, stream>>>(deg, rowptr, bsum, dinv);
    k_scanB  <<<1, dim3(128), 0, stream>>>(bsum, boff, rowptr);
    k_scanC  <<<391, blk, 0, stream>>>(rowptr, boff, csr);
    k_fill   <<<8 * KB, blk, 0, stream>>>(gcnt, binbuf, blockhist, rowptr, csr);

    const unsigned short* lin[4] = {xb, h[0], h[1], h[2]};
    for (int l = 0; l < 4; ++l) {
        k_mmf<<<1563, blk, 0, stream>>>(lin[l], WT + (size_t)l * 128 * 128, dinv,
                                        (uint4*)bufM);
        k_agg<<<25000, blk, 0, stream>>>(rowptr, csr, (const uint4*)bufM, dinv,
                                         b[l], (uint4*)h[l]);
    }
    k_jk4<<<1563, blk, 0, stream>>>(h[0], h[1], h[2], h[3], WjT, linb, out);
}

// Round 17
// 451.002 us; speedup vs baseline: 1.1149x; 1.1149x over previous
//
#include <hip/hip_runtime.h>
#include <cstdint>
#include <cstddef>

#define NN 100000
#define NE 1600000
#define NTOT (NE + NN)      // 1700000 edges incl self-loops
#define HF 128
#define OF 64
#define SHARD 12500         // NN/8 dst-range per XCD
#define BCHUNK 2048         // edges per k_bin block
#define BCAP 210000         // per-shard bin capacity (mean 200K, +24 sigma)
#define KB 32               // blocks per shard in cnt/fill

// Hidden-feature buffers (xb, m, h_l) use the MFMA-native PERMUTED layout:
// stored position p holds logical col c with p = (c&15)*8 + (c>>4),
// i.e. c = (p&7)*16 + (p>>3). W/Wjk get the inverse permutation on their
// k-dim in k_prep, so all matmuls are invariant.

typedef short bfrag_t __attribute__((ext_vector_type(8)));   // 8 bf16 = 4 VGPR
typedef float f4v     __attribute__((ext_vector_type(4)));   // MFMA acc

// ---------------- helpers ----------------

__device__ __forceinline__ unsigned int f2bf_rne(float f) {
    unsigned int u = __float_as_uint(f);
    return (u + 0x7fffu + ((u >> 16) & 1u)) >> 16;
}
__device__ __forceinline__ unsigned int pack_bf2(float lo, float hi) {
    return f2bf_rne(lo) | (f2bf_rne(hi) << 16);
}

// ---------------- graph preprocessing ----------------

__global__ __launch_bounds__(64) void k_init(int* gcnt) {
    if (threadIdx.x < 8) gcnt[threadIdx.x] = 0;
}

__device__ __forceinline__ int nt_load(const int* p) {
    return __builtin_nontemporal_load(p);
}

// Single-pass shard binning with per-block int64/int32 self-detection.
__global__ __launch_bounds__(256) void k_bin(const int* __restrict__ ei,
                                             int* __restrict__ gcnt,
                                             uint2* __restrict__ binbuf) {
    __shared__ uint2 bins[8][640];     // 40 KB; 640 cap = +32 sigma vs mean 256
    __shared__ int cnt[8], base[8], anynz;
    int tid = threadIdx.x;
    if (tid < 8) cnt[tid] = 0;
    if (tid == 0) anynz = 0;
    __syncthreads();
    int ebeg = blockIdx.x * BCHUNK;
    int eend = min(NE, ebeg + BCHUNK);
    int v = 0;
    for (int e = ebeg + tid; e < eend; e += 256) v |= nt_load(&ei[2 * e + 1]);
    if (v) anynz = 1;                  // benign race: all writers store 1
    __syncthreads();
    bool is64 = (anynz == 0);
    for (int e = ebeg + tid; e < eend; e += 256) {
        int d = is64 ? nt_load(&ei[2 * (NE + e)]) : nt_load(&ei[NE + e]);
        int s = is64 ? nt_load(&ei[2 * e])        : nt_load(&ei[e]);
        int x = (unsigned)d / SHARD;
        int p = atomicAdd(&cnt[x], 1);
        if (p < 640) bins[x][p] = make_uint2((unsigned)d, (unsigned)s);
    }
    __syncthreads();
    if (tid < 8) {
        int c = min(cnt[tid], 640);
        cnt[tid] = c;
        base[tid] = atomicAdd(&gcnt[tid], c);
    }
    __syncthreads();
    for (int x = 0; x < 8; ++x) {
        int c = cnt[x], b0 = base[x];
        for (int i = tid; i < c; i += 256)
            if (b0 + i < BCAP) binbuf[(size_t)x * BCAP + b0 + i] = bins[x][i];
    }
}

// Pass A: per-(shard,block) LDS count-histogram of its record chunk.
__global__ __launch_bounds__(256) void k_cnt(const int* __restrict__ gcnt,
                                             const uint2* __restrict__ binbuf,
                                             int* __restrict__ blockhist) {
    __shared__ int hist[SHARD];        // 50 KB
    int tid = threadIdx.x;
    int x = blockIdx.x & 7, kb = blockIdx.x >> 3;
    int n = min(gcnt[x], BCAP);
    int chunk = (n + KB - 1) / KB;
    int beg = kb * chunk, end = min(n, beg + chunk);
    for (int i = tid; i < SHARD; i += 256) hist[i] = 0;
    __syncthreads();
    for (int i = beg + tid; i < end; i += 256) {
        uint2 r = binbuf[(size_t)x * BCAP + i];
        atomicAdd(&hist[r.x - (unsigned)x * SHARD], 1);
    }
    __syncthreads();
    int* bh = blockhist + ((size_t)x * KB + kb) * SHARD;
    for (int i = tid; i < SHARD; i += 256) bh[i] = hist[i];
}

// Column scan: per node, exclusive-scan the KB per-block counts (in place)
// and write deg = 1 + total (self-loop).
__global__ __launch_bounds__(256) void k_colscan(int* __restrict__ blockhist,
                                                 int* __restrict__ deg) {
    int i = blockIdx.x * 256 + threadIdx.x;
    if (i >= NN) return;
    int x = i / SHARD, ln = i % SHARD;
    int* col = blockhist + (size_t)x * KB * SHARD + ln;
    int s = 0;
#pragma unroll
    for (int kb = 0; kb < KB; ++kb) {
        int c = col[(size_t)kb * SHARD];
        col[(size_t)kb * SHARD] = s;
        s += c;
    }
    deg[i] = 1 + s;
}

// exclusive scan of deg[N] -> rowptr (partial), also dinv = rsqrt(deg)
__global__ __launch_bounds__(256) void k_scanA(const int* deg, int* rowptr, int* bsum,
                                               float* dinv) {
    __shared__ int sh[256];
    int tid = threadIdx.x;
    int base = blockIdx.x * 1024 + tid * 4;
    int v0 = 0, v1 = 0, v2 = 0, v3 = 0;
    if (base + 0 < NN) v0 = deg[base + 0];
    if (base + 1 < NN) v1 = deg[base + 1];
    if (base + 2 < NN) v2 = deg[base + 2];
    if (base + 3 < NN) v3 = deg[base + 3];
    if (base + 0 < NN) dinv[base + 0] = rsqrtf((float)v0);
    if (base + 1 < NN) dinv[base + 1] = rsqrtf((float)v1);
    if (base + 2 < NN) dinv[base + 2] = rsqrtf((float)v2);
    if (base + 3 < NN) dinv[base + 3] = rsqrtf((float)v3);
    int s = v0 + v1 + v2 + v3;
    sh[tid] = s;
    __syncthreads();
    for (int off = 1; off < 256; off <<= 1) {
        int t = (tid >= off) ? sh[tid - off] : 0;
        __syncthreads();
        sh[tid] += t;
        __syncthreads();
    }
    int run = sh[tid] - s;
    if (base + 0 < NN) rowptr[base + 0] = run; run += v0;
    if (base + 1 < NN) rowptr[base + 1] = run; run += v1;
    if (base + 2 < NN) rowptr[base + 2] = run; run += v2;
    if (base + 3 < NN) rowptr[base + 3] = run;
    if (tid == 255) bsum[blockIdx.x] = sh[255];
}

__global__ __launch_bounds__(128) void k_scanB(const int* bsum, int* boff, int* rowptr) {
    __shared__ int sh[128];
    int tid = threadIdx.x;
    int v = (tid < 98) ? bsum[tid] : 0;
    sh[tid] = v;
    __syncthreads();
    for (int off = 1; off < 128; off <<= 1) {
        int t = (tid >= off) ? sh[tid - off] : 0;
        __syncthreads();
        sh[tid] += t;
        __syncthreads();
    }
    if (tid < 98) boff[tid] = sh[tid] - v;
    if (tid == 0) rowptr[NN] = NTOT;
}

// finalize rowptr AND place the self-loop in slot 0 of each row
__global__ __launch_bounds__(256) void k_scanC(int* rowptr, const int* boff, int* csr) {
    int i = blockIdx.x * 256 + threadIdx.x;
    if (i < NN) {
        int r = rowptr[i] + boff[i >> 10];
        rowptr[i] = r;
        csr[r] = i;          // self-loop (edge ranks start at 1)
    }
}

// Pass B: re-read records, assign local ranks via LDS atomics, write csr.
__global__ __launch_bounds__(256) void k_fill(const int* __restrict__ gcnt,
                                              const uint2* __restrict__ binbuf,
                                              const int* __restrict__ blockhist,
                                              const int* __restrict__ rowptr,
                                              int* __restrict__ csr) {
    __shared__ int lrank[SHARD];       // 50 KB
    int tid = threadIdx.x;
    int x = blockIdx.x & 7, kb = blockIdx.x >> 3;
    int n = min(gcnt[x], BCAP);
    int chunk = (n + KB - 1) / KB;
    int beg = kb * chunk, end = min(n, beg + chunk);
    for (int i = tid; i < SHARD; i += 256) lrank[i] = 0;
    __syncthreads();
    const int* bh = blockhist + ((size_t)x * KB + kb) * SHARD;
    for (int i = beg + tid; i < end; i += 256) {
        uint2 r = binbuf[(size_t)x * BCAP + i];
        int ln = r.x - (unsigned)x * SHARD;
        int lr = atomicAdd(&lrank[ln], 1);
        csr[rowptr[r.x] + 1 + bh[ln] + lr] = (int)r.y;
    }
}

// ---------------- x f32 -> bf16, PERMUTED layout ----------------
__global__ __launch_bounds__(256) void k_xcvt(const float* __restrict__ x,
                                              uint4* __restrict__ xb4) {
    int t = blockIdx.x * 256 + threadIdx.x;
    if (t >= NN * 16) return;
    int row = t >> 4, lj = t & 15;
    const float* xr = x + (size_t)row * 128 + lj;
    uint4 o;
    o.x = pack_bf2(xr[0],  xr[16]);
    o.y = pack_bf2(xr[32], xr[48]);
    o.z = pack_bf2(xr[64], xr[80]);
    o.w = pack_bf2(xr[96], xr[112]);
    xb4[(size_t)row * 16 + lj] = o;
}

// ---------------- weight prep: bf16 + transpose + k-dim permutation ----------------
__global__ __launch_bounds__(256) void k_prep(const float* __restrict__ W0,
                                              const float* __restrict__ W1,
                                              const float* __restrict__ W2,
                                              const float* __restrict__ W3,
                                              const float* __restrict__ linW,
                                              unsigned short* __restrict__ WT,
                                              unsigned short* __restrict__ WjT) {
    int idx = blockIdx.x * 256 + threadIdx.x;
    if (idx < 4 * 128 * 128) {
        int l = idx >> 14, r = idx & 16383, n = r >> 7, p = r & 127;
        int c = (p & 7) * 16 + (p >> 3);
        const float* Wl = (l == 0) ? W0 : (l == 1) ? W1 : (l == 2) ? W2 : W3;
        WT[idx] = (unsigned short)f2bf_rne(Wl[c * 128 + n]);
    } else if (idx < 4 * 128 * 128 + 4 * 64 * 128) {
        int i2 = idx - 65536;
        int l = i2 >> 13, r = i2 & 8191, n = r >> 7, p = r & 127;
        int c = (p & 7) * 16 + (p >> 3);
        WjT[i2] = (unsigned short)f2bf_rne(linW[(size_t)(l * 128 + c) * 64 + n]);
    }
}

// ---------------- MFMA matmul: m = bf16(dinv * (A @ W)), permuted I/O ----------------
__global__ __launch_bounds__(256) void k_mmf(const unsigned short* __restrict__ A,
                                             const unsigned short* __restrict__ WT,
                                             const float* __restrict__ dinv,
                                             uint4* __restrict__ m4o) {
    __shared__ unsigned short Wlds[128 * 128];   // 32 KB
    int tid = threadIdx.x;
    int row0 = blockIdx.x * 64;

    for (int c = tid; c < 2048; c += 256) {       // W^T, swizzled
        int row = c >> 4, c16 = c & 15;
        uint4 v = *(const uint4*)&WT[row * 128 + c16 * 8];
        *(uint4*)((char*)Wlds + row * 256 + ((c16 * 16) ^ ((row & 7) << 4))) = v;
    }

    int lane = tid & 63, w = tid >> 6;
    int r15 = lane & 15, q = lane >> 4;
    int xo = (r15 & 7) << 4;

    int arow = row0 + 16 * w + r15;
    bool av = arow < NN;
    bfrag_t afr[4];
#pragma unroll
    for (int ks = 0; ks < 4; ++ks) {
        bfrag_t z = {0, 0, 0, 0, 0, 0, 0, 0};
        afr[ks] = av ? *(const bfrag_t*)&A[(size_t)arow * 128 + ks * 32 + q * 8] : z;
    }
    __syncthreads();

    f4v acc[8];
#pragma unroll
    for (int i = 0; i < 8; ++i) acc[i] = (f4v){0.f, 0.f, 0.f, 0.f};

#pragma unroll
    for (int ks = 0; ks < 4; ++ks) {
        int ko = ks * 64 + q * 16;
#pragma unroll
        for (int nb = 0; nb < 8; ++nb) {
            bfrag_t b = *(const bfrag_t*)((const char*)Wlds + (nb * 16 + r15) * 256 + (ko ^ xo));
            acc[nb] = __builtin_amdgcn_mfma_f32_16x16x32_bf16(afr[ks], b, acc[nb], 0, 0, 0);
        }
    }

#pragma unroll
    for (int reg = 0; reg < 4; ++reg) {
        int gr = row0 + 16 * w + q * 4 + reg;
        if (gr < NN) {
            float sc = dinv[gr];
            uint4 o;
            o.x = pack_bf2(acc[0][reg] * sc, acc[1][reg] * sc);
            o.y = pack_bf2(acc[2][reg] * sc, acc[3][reg] * sc);
            o.z = pack_bf2(acc[4][reg] * sc, acc[5][reg] * sc);
            o.w = pack_bf2(acc[6][reg] * sc, acc[7][reg] * sc);
            m4o[(size_t)gr * 16 + r15] = o;      // stored positions r15*8..+7
        }
    }
}

// h_out[d][:] = bf16(relu(dinv[d] * sum_s m[s][:] + b)), permuted layout.
// R15-proven structure: one wave per node; ONE coalesced 64-wide csr load per
// chunk + wave-uniform __shfl distribution; 4 groups of 16 lanes each gather
// a full 256 B row (16 B/lane); 16-edge inner step = 4 gathers in flight.
// All __shfl executed by ALL lanes (wave-uniform, clamped indices).
__global__ __launch_bounds__(256) void k_agg(const int* __restrict__ rowptr,
                                             const int* __restrict__ csr,
                                             const uint4* __restrict__ m4,
                                             const float* __restrict__ dinv,
                                             const float* __restrict__ bias,
                                             uint4* __restrict__ outb) {
    int w = threadIdx.x >> 6, lane = threadIdx.x & 63;
    int grp = lane >> 4, lj = lane & 15;
    int node = blockIdx.x * 4 + w;
    if (node >= NN) return;
    int beg = rowptr[node], end = rowptr[node + 1];

    float a[8];
#pragma unroll
    for (int q = 0; q < 8; ++q) a[q] = 0.f;

    auto acc8 = [&](uint4 v) {
        a[0] += __uint_as_float(v.x << 16);
        a[1] += __uint_as_float(v.x & 0xffff0000u);
        a[2] += __uint_as_float(v.y << 16);
        a[3] += __uint_as_float(v.y & 0xffff0000u);
        a[4] += __uint_as_float(v.z << 16);
        a[5] += __uint_as_float(v.z & 0xffff0000u);
        a[6] += __uint_as_float(v.w << 16);
        a[7] += __uint_as_float(v.w & 0xffff0000u);
    };

    for (int base = beg; base < end; base += 64) {
        int cnt = min(64, end - base);
        int sv = (lane < cnt) ? csr[base + lane] : 0;
        int k = 0;
        for (; k + 16 <= cnt; k += 16) {
            int s0 = __shfl(sv, k + grp);
            int s1 = __shfl(sv, k + 4 + grp);
            int s2 = __shfl(sv, k + 8 + grp);
            int s3 = __shfl(sv, k + 12 + grp);
            uint4 v0 = m4[(size_t)s0 * 16 + lj];
            uint4 v1 = m4[(size_t)s1 * 16 + lj];
            uint4 v2 = m4[(size_t)s2 * 16 + lj];
            uint4 v3 = m4[(size_t)s3 * 16 + lj];
            acc8(v0); acc8(v1); acc8(v2); acc8(v3);
        }
        for (; k + 4 <= cnt; k += 4) {      // wave-uniform
            int s = __shfl(sv, k + grp);
            uint4 v = m4[(size_t)s * 16 + lj];
            acc8(v);
        }
        int rem = cnt - k;                  // 0..3
        if (rem) {                          // wave-uniform
            int idx = k + grp;
            if (idx >= cnt) idx = cnt - 1;  // clamp; shuffle by ALL lanes
            int s = __shfl(sv, idx);
            if (grp < rem) {                // only accumulate predicated
                uint4 v = m4[(size_t)s * 16 + lj];
                acc8(v);
            }
        }
    }
#pragma unroll
    for (int q = 0; q < 8; ++q) a[q] += __shfl_xor(a[q], 16);
#pragma unroll
    for (int q = 0; q < 8; ++q) a[q] += __shfl_xor(a[q], 32);

    if (grp == 0) {
        float sc = dinv[node];
        float r[8];
#pragma unroll
        for (int q = 0; q < 8; ++q)
            r[q] = fmaxf(a[q] * sc + bias[q * 16 + lj], 0.f);   // logical col q*16+lj
        uint4 o;
        o.x = pack_bf2(r[0], r[1]);
        o.y = pack_bf2(r[2], r[3]);
        o.z = pack_bf2(r[4], r[5]);
        o.w = pack_bf2(r[6], r[7]);
        outb[(size_t)node * 16 + lj] = o;
    }
}

// ---------------- final: logits = sum_l h_l @ Wjk_l + linb; log_softmax ----------------
__global__ __launch_bounds__(256) void k_jk4(const unsigned short* __restrict__ h0,
                                             const unsigned short* __restrict__ h1,
                                             const unsigned short* __restrict__ h2,
                                             const unsigned short* __restrict__ h3,
                                             const unsigned short* __restrict__ WjT,
                                             const float* __restrict__ linb,
                                             float* __restrict__ out) {
    __shared__ unsigned short Wjlds[4 * 64 * 128];   // 64 KB, swizzled
    int tid = threadIdx.x;
    int row0 = blockIdx.x * 64;

    for (int c = tid; c < 4096; c += 256) {      // 256 rows (l*64+n) x 128
        int row = c >> 4, c16 = c & 15;
        uint4 v = *(const uint4*)&WjT[row * 128 + c16 * 8];
        *(uint4*)((char*)Wjlds + row * 256 + ((c16 * 16) ^ ((row & 7) << 4))) = v;
    }

    int lane = tid & 63, w = tid >> 6;
    int r15 = lane & 15, q = lane >> 4;
    int xo = (r15 & 7) << 4;
    int arow = row0 + 16 * w + r15;
    bool av = arow < NN;
    const unsigned short* hs[4] = {h0, h1, h2, h3};

    __syncthreads();

    f4v accj[4];
#pragma unroll
    for (int i = 0; i < 4; ++i) accj[i] = (f4v){0.f, 0.f, 0.f, 0.f};

#pragma unroll
    for (int l = 0; l < 4; ++l) {
        bfrag_t afr[4];
#pragma unroll
        for (int ks = 0; ks < 4; ++ks) {
            bfrag_t z = {0, 0, 0, 0, 0, 0, 0, 0};
            afr[ks] = av ? *(const bfrag_t*)&hs[l][(size_t)arow * 128 + ks * 32 + q * 8] : z;
        }
#pragma unroll
        for (int ks = 0; ks < 4; ++ks) {
            int ko = ks * 64 + q * 16;
#pragma unroll
            for (int jb = 0; jb < 4; ++jb) {
                bfrag_t b = *(const bfrag_t*)((const char*)Wjlds
                            + (l * 64 + jb * 16 + r15) * 256 + (ko ^ xo));
                accj[jb] = __builtin_amdgcn_mfma_f32_16x16x32_bf16(afr[ks], b, accj[jb], 0, 0, 0);
            }
        }
    }

#pragma unroll
    for (int reg = 0; reg < 4; ++reg) {
        int gr = row0 + 16 * w + q * 4 + reg;    // uniform across the 16-lane group
        float v0 = accj[0][reg] + linb[r15];
        float v1 = accj[1][reg] + linb[16 + r15];
        float v2 = accj[2][reg] + linb[32 + r15];
        float v3 = accj[3][reg] + linb[48 + r15];
        float mx = fmaxf(fmaxf(v0, v1), fmaxf(v2, v3));
#pragma unroll
        for (int s = 1; s < 16; s <<= 1) mx = fmaxf(mx, __shfl_xor(mx, s, 16));
        float sum = expf(v0 - mx) + expf(v1 - mx) + expf(v2 - mx) + expf(v3 - mx);
#pragma unroll
        for (int s = 1; s < 16; s <<= 1) sum += __shfl_xor(sum, s, 16);
        float ls = logf(sum) + mx;
        if (gr < NN) {
            out[(size_t)gr * 64 + r15]      = v0 - ls;
            out[(size_t)gr * 64 + 16 + r15] = v1 - ls;
            out[(size_t)gr * 64 + 32 + r15] = v2 - ls;
            out[(size_t)gr * 64 + 48 + r15] = v3 - ls;
        }
    }
}

// ---------------- launch ----------------

extern "C" void kernel_launch(void* const* d_in, const int* in_sizes, int n_in,
                              void* d_out, int out_size, void* d_ws, size_t ws_size,
                              hipStream_t stream) {
    const float* x    = (const float*)d_in[0];
    const int*   ei   = (const int*)d_in[1];
    const float* W[4] = {(const float*)d_in[2], (const float*)d_in[4],
                         (const float*)d_in[6], (const float*)d_in[8]};
    const float* b[4] = {(const float*)d_in[3], (const float*)d_in[5],
                         (const float*)d_in[7], (const float*)d_in[9]};
    const float* linW = (const float*)d_in[10];
    const float* linb = (const float*)d_in[11];
    float* out = (float*)d_out;

    char* wp = (char*)d_ws;
    auto alloc = [&](size_t bytes) {
        void* p = (void*)wp;
        wp += (bytes + 255) & ~(size_t)255;
        return p;
    };
    int*   gcnt    = (int*)  alloc(32);
    int*   deg     = (int*)  alloc((size_t)NN * 4);
    float* dinv    = (float*)alloc((size_t)NN * 4);
    int*   rowptr  = (int*)  alloc((size_t)(NN + 1) * 4);
    int*   bsum    = (int*)  alloc(512);
    int*   boff    = (int*)  alloc(512);
    int*   csr     = (int*)  alloc((size_t)NTOT * 4);
    uint2* binbuf  = (uint2*)alloc((size_t)8 * BCAP * 8);
    int*   blockhist = (int*)alloc((size_t)8 * KB * SHARD * 4);   // 12.8 MB
    unsigned short* WT  = (unsigned short*)alloc((size_t)4 * 128 * 128 * 2);
    unsigned short* WjT = (unsigned short*)alloc((size_t)4 * 64 * 128 * 2);
    unsigned short* xb   = (unsigned short*)alloc((size_t)NN * 128 * 2);  // permuted x
    unsigned short* bufM = (unsigned short*)alloc((size_t)NN * 128 * 2);  // messages
    unsigned short* h[4];
    for (int l = 0; l < 4; ++l)
        h[l] = (unsigned short*)alloc((size_t)NN * 128 * 2);              // bf16 h_l

    dim3 blk(256);
    k_init   <<<1, dim3(64), 0, stream>>>(gcnt);
    k_prep   <<<384, blk, 0, stream>>>(W[0], W[1], W[2], W[3], linW, WT, WjT);
    k_xcvt   <<<6250, blk, 0, stream>>>(x, (uint4*)xb);
    k_bin    <<<(NE + BCHUNK - 1) / BCHUNK, blk, 0, stream>>>(ei, gcnt, binbuf);
    k_cnt    <<<8 * KB, blk, 0, stream>>>(gcnt, binbuf, blockhist);
    k_colscan<<<391, blk, 0, stream>>>(blockhist, deg);
    k_scanA  <<<98, blk, 0, stream>>>(deg, rowptr, bsum, dinv);
    k_scanB  <<<1, dim3(128), 0, stream>>>(bsum, boff, rowptr);
    k_scanC  <<<391, blk, 0, stream>>>(rowptr, boff, csr);
    k_fill   <<<8 * KB, blk, 0, stream>>>(gcnt, binbuf, blockhist, rowptr, csr);

    const unsigned short* lin[4] = {xb, h[0], h[1], h[2]};
    for (int l = 0; l < 4; ++l) {
        k_mmf<<<1563, blk, 0, stream>>>(lin[l], WT + (size_t)l * 128 * 128, dinv,
                                        (uint4*)bufM);
        k_agg<<<25000, blk, 0, stream>>>(rowptr, csr, (const uint4*)bufM, dinv,
                                         b[l], (uint4*)h[l]);
    }
    k_jk4<<<1563, blk, 0, stream>>>(h[0], h[1], h[2], h[3], WjT, linb, out);
}